// Round 5
// baseline (711.292 us; speedup 1.0000x reference)
//
#include <hip/hip_runtime.h>
#include <math.h>

#define T_ 128

// ws offsets (floats)
#define OFF_M2      0         // [256][256]
#define OFF_WCOMBT  65536     // [128][1280]
#define OFF_BIAS    229376    // [1280]
#define OFF_WCT     230656    // [256][128]
#define OFF_XG2     263424    // [128 t][4 g][32 cb][32 lc][8 b]
#define OFF_BX2     4457728   // [128 t][4 g][256 col][8 b]
#define OFF_HSEQ    5506304   // [128 t][4 g][8 b][256]  (ht from LSTM chain)
#define OFF_HCSEQ   6554880   // [128 t][4 g][8 b][256]  (hn_partial from cfc chain)

#define SENTB 0xFFFFFFFFu

__device__ __forceinline__ float sigm_f(float x) { return 1.0f / (1.0f + __expf(-x)); }
__device__ __forceinline__ float tanh_f(float x) { return 1.0f - 2.0f / (__expf(2.0f * x) + 1.0f); }

__device__ __forceinline__ unsigned long long aload_u64(const unsigned long long* p) {
  return __hip_atomic_load(p, __ATOMIC_RELAXED, __HIP_MEMORY_SCOPE_AGENT);
}
__device__ __forceinline__ void astore_f(float* p, float v) {
  __hip_atomic_store(p, v, __ATOMIC_RELAXED, __HIP_MEMORY_SCOPE_AGENT);
}
__device__ __forceinline__ bool bad_u64(unsigned long long v) {
  return (unsigned)v == SENTB || (unsigned)(v >> 32) == SENTB;
}

// ---------------- pack: WcombT, bias, W_C^T ----------------
__global__ __launch_bounds__(256) void pack_kernel(
    const float* __restrict__ W_ih, const float* __restrict__ W_B,
    const float* __restrict__ b_ih, const float* __restrict__ b_hh,
    const float* __restrict__ b_B,  const float* __restrict__ W_C,
    float* __restrict__ ws) {
  int idx = blockIdx.x * 256 + threadIdx.x;
  if (idx < 163840) {  // WcombT[k][c]
    int k = idx / 1280, c = idx - k * 1280;
    ws[OFF_WCOMBT + idx] = (c < 1024) ? W_ih[c * 128 + k] : W_B[(c - 1024) * 128 + k];
    return;
  }
  idx -= 163840;
  if (idx < 1280) {
    ws[OFF_BIAS + idx] = (idx < 1024) ? (b_ih[idx] + b_hh[idx]) : b_B[idx - 1024];
    return;
  }
  idx -= 1280;
  if (idx < 32768) {  // W_CT[k][o]
    int k = idx >> 7, o = idx & 127;
    ws[OFF_WCT + idx] = W_C[o * 256 + k];
  }
}

// ---------------- M2 = (W_A D)(W_A D), D = diag(1/tau) ----------------
__global__ __launch_bounds__(256) void m2_kernel(
    const float* __restrict__ W_A, const float* __restrict__ tau,
    float* __restrict__ M2) {
  __shared__ float adrow[256];
  const int i = blockIdx.x, k = threadIdx.x;
  const float itk = 1.0f / tau[k];
  adrow[k] = W_A[i * 256 + k] * itk;
  __syncthreads();
  float s = 0.f;
#pragma unroll 8
  for (int m = 0; m < 256; ++m)
    s = fmaf(adrow[m], W_A[m * 256 + k], s);
  M2[i * 256 + k] = s * itk;
}

// ---------------- xg/Bx precompute, recur-native layout ----------------
__global__ __launch_bounds__(256) void xgt_kernel(
    const float* __restrict__ x, const float* __restrict__ WT,
    const float* __restrict__ bias, float* __restrict__ xg2,
    float* __restrict__ bx2) {
  __shared__ float xs[8 * 128];
  const int tid = threadIdx.x;
  const int rt = blockIdx.x, ct = blockIdx.y;
  ((float4*)xs)[tid] = ((const float4*)(x + rt * 1024))[tid];
  __syncthreads();
  const int r = tid >> 5, cg = tid & 31;
  const int c0 = ct * 256 + cg * 8;
  const float4* b4 = (const float4*)(bias + c0);
  float4 bA = b4[0], bB = b4[1];
  float a[8] = {bA.x, bA.y, bA.z, bA.w, bB.x, bB.y, bB.z, bB.w};
  const float4* xr4 = (const float4*)(xs + r * 128);
#pragma unroll 4
  for (int k4 = 0; k4 < 32; ++k4) {
    float4 xv = xr4[k4];
#define STEPB(kk, comp)                                                      \
    {                                                                        \
      const float4* w = (const float4*)(WT + (k4 * 4 + kk) * 1280 + c0);     \
      float4 wA = w[0], wB = w[1];                                           \
      a[0] = fmaf(wA.x, comp, a[0]); a[1] = fmaf(wA.y, comp, a[1]);          \
      a[2] = fmaf(wA.z, comp, a[2]); a[3] = fmaf(wA.w, comp, a[3]);          \
      a[4] = fmaf(wB.x, comp, a[4]); a[5] = fmaf(wB.y, comp, a[5]);          \
      a[6] = fmaf(wB.z, comp, a[6]); a[7] = fmaf(wB.w, comp, a[7]);          \
    }
    STEPB(0, xv.x) STEPB(1, xv.y) STEPB(2, xv.z) STEPB(3, xv.w)
#undef STEPB
  }
  const int row = rt * 8 + r;          // = b*128 + t
  const int b = row >> 7, t = row & 127;
  const int g = b >> 3, bl = b & 7;
  if (ct < 4) {
    const size_t base = ((size_t)((t * 4 + g) * 32 + cg)) * 256 + ct * 64 + bl;
#pragma unroll
    for (int i = 0; i < 8; ++i) xg2[base + i * 8] = a[i];
  } else {
    const size_t base = ((size_t)(t * 4 + g) * 256 + cg * 8) * 8 + bl;
#pragma unroll
    for (int i = 0; i < 8; ++i) bx2[base + i * 8] = a[i];
  }
}

// ---------------- recurrence, split chains: blocks 0-127 = LSTM, 128-255 = cfc ----
__global__ __launch_bounds__(256) void recur_split_kernel(
    const float* __restrict__ ts_all, const float* __restrict__ tau,
    const float* __restrict__ sigma, const float* __restrict__ W_hh,
    const float* __restrict__ W_A, const float* __restrict__ M2,
    const float* __restrict__ xg2, const float* __restrict__ bx2,
    float* __restrict__ hseq, float* __restrict__ hcseq) {
  const int bid = blockIdx.x & 127;
  const int g = bid >> 5, cb = bid & 31;
  const int tid = threadIdx.x;

  __shared__ float h_s[8][256];       // lstm: staged h state (cfc: true hc state)
  __shared__ float q_s[8][768];       // cfc only
  __shared__ float gdot_s[256];       // lstm only
  __shared__ float redg[16 * 297];    // lstm only
  __shared__ float redc[4][4][2][8];  // cfc only
  __shared__ float cst_s[64];         // lstm only (wave0-private)
  __shared__ float isig_s[256];       // cfc only

  const unsigned long long* hsq  = (const unsigned long long*)hseq;
  const unsigned long long* hcsq = (const unsigned long long*)hcseq;

  if (blockIdx.x < 128) {
    // ===================== LSTM chain =====================
    const int cg = tid & 15, kq = tid >> 4;
    float wg[2][16];
#pragma unroll
    for (int c = 0; c < 2; ++c) {
      const int lc = cg + 16 * c;
      const int grow = (lc >> 3) * 256 + 8 * cb + (lc & 7);
      const float4* src = (const float4*)(W_hh + grow * 256 + kq * 16);
#pragma unroll
      for (int k4 = 0; k4 < 4; ++k4) {
        float4 v = src[k4];
        wg[c][4 * k4 + 0] = v.x; wg[c][4 * k4 + 1] = v.y;
        wg[c][4 * k4 + 2] = v.z; wg[c][4 * k4 + 3] = v.w;
      }
    }
    if (tid < 64) cst_s[tid] = 0.f;  // wave0-private, no barrier needed

    for (int t = 0; t < T_; ++t) {
      const float xg_v = xg2[((size_t)((t * 4 + g) * 32 + cb)) * 256 + tid];

      if (t == 0) {
        const float2 z = make_float2(0.f, 0.f);
#pragma unroll
        for (int v = 0; v < 4; ++v)
          ((float2*)&h_s[0][0])[v * 256 + tid] = z;
      } else {
        const unsigned long long* hp = hsq + (size_t)((t - 1) * 4 + g) * 1024 + tid;
        unsigned long long hv[4];
        // depth-2 pipelined poll: two rounds in flight, check alternately.
        unsigned long long A0, A1, A2, A3, B0, B1, B2, B3;
#define LD4A { A0 = aload_u64(hp); A1 = aload_u64(hp + 256);                 \
               A2 = aload_u64(hp + 512); A3 = aload_u64(hp + 768); }
#define LD4B { B0 = aload_u64(hp); B1 = aload_u64(hp + 256);                 \
               B2 = aload_u64(hp + 512); B3 = aload_u64(hp + 768); }
        LD4A; LD4B;
        int spins = 0;
        for (;;) {
          if (!(bad_u64(A0) || bad_u64(A1) || bad_u64(A2) || bad_u64(A3))) {
            hv[0] = A0; hv[1] = A1; hv[2] = A2; hv[3] = A3; break;
          }
          LD4A;
          if (!(bad_u64(B0) || bad_u64(B1) || bad_u64(B2) || bad_u64(B3))) {
            hv[0] = B0; hv[1] = B1; hv[2] = B2; hv[3] = B3; break;
          }
          LD4B;
          if (++spins > 24) __builtin_amdgcn_s_sleep(1);
        }
#undef LD4A
#undef LD4B
#pragma unroll
        for (int v = 0; v < 4; ++v) {
          const int flat = v * 256 + tid, b = flat >> 7, k2 = flat & 127;
          union { unsigned long long u; float2 f; } H; H.u = hv[v];
          ((float2*)&h_s[b][0])[k2] = H.f;
        }
      }
      __syncthreads();

      // gates matvec: 16 lanes (same kq) broadcast-read the same h float4s
      float accg[2][8];
#pragma unroll
      for (int b = 0; b < 8; ++b) {
        const float4* h4p = (const float4*)&h_s[b][kq << 4];
        const float4 x0 = h4p[0], x1 = h4p[1], x2 = h4p[2], x3 = h4p[3];
#pragma unroll
        for (int c = 0; c < 2; ++c) {
          float s = wg[c][0] * x0.x;
          s = fmaf(wg[c][1],  x0.y, s); s = fmaf(wg[c][2],  x0.z, s);
          s = fmaf(wg[c][3],  x0.w, s); s = fmaf(wg[c][4],  x1.x, s);
          s = fmaf(wg[c][5],  x1.y, s); s = fmaf(wg[c][6],  x1.z, s);
          s = fmaf(wg[c][7],  x1.w, s); s = fmaf(wg[c][8],  x2.x, s);
          s = fmaf(wg[c][9],  x2.y, s); s = fmaf(wg[c][10], x2.z, s);
          s = fmaf(wg[c][11], x2.w, s); s = fmaf(wg[c][12], x3.x, s);
          s = fmaf(wg[c][13], x3.y, s); s = fmaf(wg[c][14], x3.z, s);
          s = fmaf(wg[c][15], x3.w, s);
          accg[c][b] = s;
        }
      }
#pragma unroll
      for (int c = 0; c < 2; ++c) {
        const int col = cg + 16 * c;
#pragma unroll
        for (int b = 0; b < 8; ++b)
          redg[kq * 297 + col * 9 + b] = accg[c][b];
      }
      __syncthreads();

      // final sum (+ xg folded in)
      {
        const int col = tid >> 3, b = tid & 7;
        float s = 0.f;
#pragma unroll
        for (int k = 0; k < 16; ++k)
          s += redg[k * 297 + col * 9 + b];
        gdot_s[tid] = s + xg_v;
      }
      __syncthreads();

      // elementwise + store ht (wave 0)
      if (tid < 64) {
        const int b = tid & 7, jj = tid >> 3;
        const float i_ = sigm_f(gdot_s[tid]);
        const float f_ = sigm_f(gdot_s[64 + tid]);
        const float g_ = tanh_f(gdot_s[128 + tid]);
        const float o_ = sigm_f(gdot_s[192 + tid]);
        const float cn = fmaf(f_, cst_s[tid], i_ * g_);
        cst_s[tid] = cn;
        const float ht = o_ * tanh_f(cn);
        astore_f(hseq + (size_t)(t * 4 + g) * 2048 + b * 256 + 8 * cb + jj, ht);
      }
      // no end-of-loop barrier (see r4 notes)
    }
  } else {
    // ===================== cfc chain =====================
    const int wv = tid >> 6, kq6 = tid & 63;
    float wc[2][12];
#pragma unroll
    for (int r = 0; r < 2; ++r) {
      const int ci = 8 * cb + 2 * wv + r;
      const float it_i = 1.0f / tau[ci];
#pragma unroll
      for (int j = 0; j < 6; ++j) {
#pragma unroll
        for (int e = 0; e < 2; ++e) {
          const int kp = 2 * kq6 + 128 * j + e;
          float v;
          if (kp < 256)      v = W_A[ci * 256 + kp] / tau[kp];
          else if (kp < 512) v = W_A[ci * 256 + (kp - 256)] * it_i;
          else               v = 0.5f * M2[ci * 256 + (kp - 512)];
          wc[r][2 * j + e] = v;
        }
      }
    }
    const float itau_comb = 1.0f / tau[8 * cb + ((tid >> 3) & 7)];
    isig_s[tid] = 1.0f / sigma[tid];
    __syncthreads();

    float (&hc_s)[8][256] = h_s;  // true hc state (partial + ht)

    for (int t = 0; t < T_; ++t) {
      float bxv = 0.f, tsb_c = 0.f;
      if (tid < 64) {
        bxv = bx2[((size_t)(t * 4 + g) * 256 + 8 * cb) * 8 + tid];
        tsb_c = ts_all[(g * 8 + (tid & 7)) * T_ + t];
      }

      if (t == 0) {
        const float2 z = make_float2(0.f, 0.f);
#pragma unroll
        for (int v = 0; v < 4; ++v) {
          const int flat = v * 256 + tid, b = flat >> 7, k2 = flat & 127;
          ((float2*)&hc_s[b][0])[k2] = z;
          float2* qrow = (float2*)&q_s[b][0];
          qrow[k2] = z; qrow[128 + k2] = z; qrow[256 + k2] = z;
        }
      } else {
        float tsb4[4];
#pragma unroll
        for (int v = 0; v < 4; ++v) {
          const int b = (v * 256 + tid) >> 7;
          tsb4[v] = ts_all[(g * 8 + b) * T_ + t];
        }
        const size_t base = (size_t)((t - 1) * 4 + g) * 1024 + tid;
        const unsigned long long* hcp = hcsq + base;  // hn_partial(t-1)
        const unsigned long long* hpp = hsq + base;   // ht(t-1)
        unsigned long long cv[4], hv[4];
        // depth-2 pipelined poll over BOTH arrays (8 u64/round, one RTT)
        unsigned long long AC0, AC1, AC2, AC3, AH0, AH1, AH2, AH3;
        unsigned long long BC0, BC1, BC2, BC3, BH0, BH1, BH2, BH3;
#define LD8A { AC0 = aload_u64(hcp); AC1 = aload_u64(hcp + 256);             \
               AC2 = aload_u64(hcp + 512); AC3 = aload_u64(hcp + 768);       \
               AH0 = aload_u64(hpp); AH1 = aload_u64(hpp + 256);             \
               AH2 = aload_u64(hpp + 512); AH3 = aload_u64(hpp + 768); }
#define LD8B { BC0 = aload_u64(hcp); BC1 = aload_u64(hcp + 256);             \
               BC2 = aload_u64(hcp + 512); BC3 = aload_u64(hcp + 768);       \
               BH0 = aload_u64(hpp); BH1 = aload_u64(hpp + 256);             \
               BH2 = aload_u64(hpp + 512); BH3 = aload_u64(hpp + 768); }
        LD8A; LD8B;
        int spins = 0;
        for (;;) {
          if (!(bad_u64(AC0) || bad_u64(AC1) || bad_u64(AC2) || bad_u64(AC3) ||
                bad_u64(AH0) || bad_u64(AH1) || bad_u64(AH2) || bad_u64(AH3))) {
            cv[0] = AC0; cv[1] = AC1; cv[2] = AC2; cv[3] = AC3;
            hv[0] = AH0; hv[1] = AH1; hv[2] = AH2; hv[3] = AH3; break;
          }
          LD8A;
          if (!(bad_u64(BC0) || bad_u64(BC1) || bad_u64(BC2) || bad_u64(BC3) ||
                bad_u64(BH0) || bad_u64(BH1) || bad_u64(BH2) || bad_u64(BH3))) {
            cv[0] = BC0; cv[1] = BC1; cv[2] = BC2; cv[3] = BC3;
            hv[0] = BH0; hv[1] = BH1; hv[2] = BH2; hv[3] = BH3; break;
          }
          LD8B;
          if (++spins > 24) __builtin_amdgcn_s_sleep(1);
        }
#undef LD8A
#undef LD8B
#pragma unroll
        for (int v = 0; v < 4; ++v) {
          const int flat = v * 256 + tid, b = flat >> 7, k2 = flat & 127;
          union { unsigned long long u; float2 f; } C, H;
          C.u = cv[v]; H.u = hv[v];
          const float2 hcv = make_float2(C.f.x + H.f.x, C.f.y + H.f.y);
          ((float2*)&hc_s[b][0])[k2] = hcv;
          const float tsb = tsb4[v];
          const float2 isg = ((const float2*)isig_s)[k2];
          float2* qrow = (float2*)&q_s[b][0];
          float2 q0 = make_float2(tsb * hcv.x, tsb * hcv.y);
          qrow[k2] = q0;
          qrow[128 + k2] = make_float2(tsb * tanh_f(hcv.x * isg.x),
                                       tsb * tanh_f(hcv.y * isg.y));
          qrow[256 + k2] = make_float2(tsb * q0.x, tsb * q0.y);
        }
      }
      __syncthreads();

      // cfc matvec: stride-paired float2 q reads
      float accc[2][8];
#pragma unroll
      for (int r = 0; r < 2; ++r)
#pragma unroll
        for (int b = 0; b < 8; ++b) accc[r][b] = 0.f;
#pragma unroll
      for (int b = 0; b < 8; ++b) {
        const float2* q2p = (const float2*)&q_s[b][0];
#pragma unroll
        for (int j = 0; j < 6; ++j) {
          const float2 qv = q2p[kq6 + 64 * j];
#pragma unroll
          for (int r = 0; r < 2; ++r) {
            accc[r][b] = fmaf(wc[r][2 * j],     qv.x, accc[r][b]);
            accc[r][b] = fmaf(wc[r][2 * j + 1], qv.y, accc[r][b]);
          }
        }
      }
#pragma unroll
      for (int r = 0; r < 2; ++r)
#pragma unroll
        for (int b = 0; b < 8; ++b) {
          float s = accc[r][b];
          s += __shfl_xor(s, 1); s += __shfl_xor(s, 2);
          s += __shfl_xor(s, 4); s += __shfl_xor(s, 8);
          accc[r][b] = s;
        }
      if ((kq6 & 15) == 0) {
        const int kqh = kq6 >> 4;
#pragma unroll
        for (int r = 0; r < 2; ++r)
#pragma unroll
          for (int b = 0; b < 8; ++b)
            redc[wv][kqh][r][b] = accc[r][b];
      }
      __syncthreads();

      // combine: store hn_partial (NO ht — consumers/out add it from hseq)
      if (tid < 64) {
        const int b = tid & 7, jj = tid >> 3;
        const int col = 8 * cb + jj;
        const int rw = jj >> 1, rr = jj & 1;
        const float dot = redc[rw][0][rr][b] + redc[rw][1][rr][b] +
                          redc[rw][2][rr][b] + redc[rw][3][rr][b];
        const float hn_p = hc_s[b][col] + dot + tsb_c * bxv * itau_comb;
        astore_f(hcseq + (size_t)(t * 4 + g) * 2048 + b * 256 + col, hn_p);
      }
      __syncthreads();  // protect hc_s (read above) vs next-iter staging writes
    }
  }
}

// ---------------- y = (hc_partial + ht) @ W_C^T + b_C ----------------
__global__ __launch_bounds__(256) void out_kernel(
    const float* __restrict__ hc, const float* __restrict__ ht,
    const float* __restrict__ WCT, const float* __restrict__ bC,
    float* __restrict__ y) {
  __shared__ float hs[16 * 256];
  const int tid = threadIdx.x;
#pragma unroll
  for (int v = 0; v < 4; ++v) {
    const int flat = v * 256 + tid;
    const int r = flat >> 6, f4 = flat & 63;
    const int row = blockIdx.x * 16 + r;   // = b*128 + t
    const int b = row >> 7, t = row & 127;
    const float4 a = ((const float4*)(hc + (size_t)(t * 32 + b) * 256))[f4];
    const float4 h = ((const float4*)(ht + (size_t)(t * 32 + b) * 256))[f4];
    ((float4*)hs)[flat] = make_float4(a.x + h.x, a.y + h.y, a.z + h.z, a.w + h.w);
  }
  __syncthreads();
  const int r = tid >> 4, cgg = tid & 15;
  const int c0 = cgg * 8;
  const float4* b4 = (const float4*)(bC + c0);
  float4 bA = b4[0], bB = b4[1];
  float a0 = bA.x, a1 = bA.y, a2 = bA.z, a3 = bA.w;
  float a4 = bB.x, a5 = bB.y, a6 = bB.z, a7 = bB.w;
  const float4* hr4 = (const float4*)(hs + r * 256);
#pragma unroll 4
  for (int k4 = 0; k4 < 64; ++k4) {
    float4 hv = hr4[k4];
#define STEPD(kk, comp)                                                     \
    {                                                                       \
      const float4* w = (const float4*)(WCT + (k4 * 4 + kk) * 128 + c0);    \
      float4 wA = w[0], wB = w[1];                                          \
      a0 = fmaf(wA.x, comp, a0); a1 = fmaf(wA.y, comp, a1);                 \
      a2 = fmaf(wA.z, comp, a2); a3 = fmaf(wA.w, comp, a3);                 \
      a4 = fmaf(wB.x, comp, a4); a5 = fmaf(wB.y, comp, a5);                 \
      a6 = fmaf(wB.z, comp, a6); a7 = fmaf(wB.w, comp, a7);                 \
    }
    STEPD(0, hv.x) STEPD(1, hv.y) STEPD(2, hv.z) STEPD(3, hv.w)
#undef STEPD
  }
  const int row = blockIdx.x * 16 + r;
  float4* dst = (float4*)(y + (size_t)row * 128 + c0);
  dst[0] = make_float4(a0, a1, a2, a3);
  dst[1] = make_float4(a4, a5, a6, a7);
}

extern "C" void kernel_launch(void* const* d_in, const int* in_sizes, int n_in,
                              void* d_out, int out_size, void* d_ws, size_t ws_size,
                              hipStream_t stream) {
  const float* x     = (const float*)d_in[0];
  const float* tspan = (const float*)d_in[1];
  const float* tau   = (const float*)d_in[2];
  const float* sigma = (const float*)d_in[3];
  const float* W_A   = (const float*)d_in[4];
  const float* W_B   = (const float*)d_in[5];
  const float* b_B   = (const float*)d_in[6];
  const float* W_C   = (const float*)d_in[7];
  const float* b_C   = (const float*)d_in[8];
  const float* W_ih  = (const float*)d_in[9];
  const float* W_hh  = (const float*)d_in[10];
  const float* b_ih  = (const float*)d_in[11];
  const float* b_hh  = (const float*)d_in[12];
  float* ws = (float*)d_ws;
  float* y = (float*)d_out;

  // sentinel-fill hseq+hcseq (0xFF bytes == SENTB dwords), 8 MB
  (void)hipMemsetAsync(ws + OFF_HSEQ, 0xFF, (size_t)2 * 1048576 * sizeof(float), stream);
  pack_kernel<<<774, 256, 0, stream>>>(W_ih, W_B, b_ih, b_hh, b_B, W_C, ws);
  m2_kernel<<<256, 256, 0, stream>>>(W_A, tau, ws + OFF_M2);
  xgt_kernel<<<dim3(512, 5), 256, 0, stream>>>(x, ws + OFF_WCOMBT, ws + OFF_BIAS,
                                               ws + OFF_XG2, ws + OFF_BX2);
  recur_split_kernel<<<256, 256, 0, stream>>>(
      tspan, tau, sigma, W_hh, W_A, ws + OFF_M2, ws + OFF_XG2, ws + OFF_BX2,
      ws + OFF_HSEQ, ws + OFF_HCSEQ);
  out_kernel<<<256, 256, 0, stream>>>(ws + OFF_HCSEQ, ws + OFF_HSEQ,
                                      ws + OFF_WCT, b_C, y);
}

// Round 6
// 482.047 us; speedup vs baseline: 1.4756x; 1.4756x over previous
//
#include <hip/hip_runtime.h>
#include <math.h>

#define T_ 128

// ws offsets (floats)
#define OFF_M2      0         // [256][256]
#define OFF_WCOMBT  65536     // [128][1280]
#define OFF_BIAS    229376    // [1280]
#define OFF_WCT     230656    // [256][128]
#define OFF_XG2     263424    // [128 t][32 b][1024 c]   (gate-major: c = gate*256+d)
#define OFF_BX2     4457728   // [128 t][32 b][256 d]
#define OFF_HSEQ    5506304   // [128 t][32 b][256 d]  (ht from LSTM chain)
#define OFF_HCSEQ   6554880   // [128 t][32 b][256 d]  (full hn from cfc chain)

#define SENTB 0xFFFFFFFFu

__device__ __forceinline__ float sigm_f(float x) { return 1.0f / (1.0f + __expf(-x)); }
__device__ __forceinline__ float tanh_f(float x) { return 1.0f - 2.0f / (__expf(2.0f * x) + 1.0f); }

__device__ __forceinline__ unsigned long long aload_u64(const unsigned long long* p) {
  return __hip_atomic_load(p, __ATOMIC_RELAXED, __HIP_MEMORY_SCOPE_AGENT);
}
__device__ __forceinline__ float aload_f(const float* p) {
  return __hip_atomic_load(p, __ATOMIC_RELAXED, __HIP_MEMORY_SCOPE_AGENT);
}
__device__ __forceinline__ void astore_f(float* p, float v) {
  __hip_atomic_store(p, v, __ATOMIC_RELAXED, __HIP_MEMORY_SCOPE_AGENT);
}
__device__ __forceinline__ bool bad_u64(unsigned long long v) {
  return (unsigned)v == SENTB || (unsigned)(v >> 32) == SENTB;
}

// ---------------- pack: WcombT, bias, W_C^T ----------------
__global__ __launch_bounds__(256) void pack_kernel(
    const float* __restrict__ W_ih, const float* __restrict__ W_B,
    const float* __restrict__ b_ih, const float* __restrict__ b_hh,
    const float* __restrict__ b_B,  const float* __restrict__ W_C,
    float* __restrict__ ws) {
  int idx = blockIdx.x * 256 + threadIdx.x;
  if (idx < 163840) {  // WcombT[k][c]
    int k = idx / 1280, c = idx - k * 1280;
    ws[OFF_WCOMBT + idx] = (c < 1024) ? W_ih[c * 128 + k] : W_B[(c - 1024) * 128 + k];
    return;
  }
  idx -= 163840;
  if (idx < 1280) {
    ws[OFF_BIAS + idx] = (idx < 1024) ? (b_ih[idx] + b_hh[idx]) : b_B[idx - 1024];
    return;
  }
  idx -= 1280;
  if (idx < 32768) {  // W_CT[k][o]
    int k = idx >> 7, o = idx & 127;
    ws[OFF_WCT + idx] = W_C[o * 256 + k];
  }
}

// ---------------- M2 = (W_A D)(W_A D), D = diag(1/tau) ----------------
__global__ __launch_bounds__(256) void m2_kernel(
    const float* __restrict__ W_A, const float* __restrict__ tau,
    float* __restrict__ M2) {
  __shared__ float adrow[256];
  const int i = blockIdx.x, k = threadIdx.x;
  const float itk = 1.0f / tau[k];
  adrow[k] = W_A[i * 256 + k] * itk;
  __syncthreads();
  float s = 0.f;
#pragma unroll 8
  for (int m = 0; m < 256; ++m)
    s = fmaf(adrow[m], W_A[m * 256 + k], s);
  M2[i * 256 + k] = s * itk;
}

// ---------------- xg/Bx precompute, batch-major layout ----------------
__global__ __launch_bounds__(256) void xgt_kernel(
    const float* __restrict__ x, const float* __restrict__ WT,
    const float* __restrict__ bias, float* __restrict__ xg2,
    float* __restrict__ bx2) {
  __shared__ float xs[8 * 128];
  const int tid = threadIdx.x;
  const int rt = blockIdx.x, ct = blockIdx.y;
  ((float4*)xs)[tid] = ((const float4*)(x + rt * 1024))[tid];
  __syncthreads();
  const int r = tid >> 5, cg = tid & 31;
  const int c0 = ct * 256 + cg * 8;
  const float4* b4 = (const float4*)(bias + c0);
  float4 bA = b4[0], bB = b4[1];
  float a[8] = {bA.x, bA.y, bA.z, bA.w, bB.x, bB.y, bB.z, bB.w};
  const float4* xr4 = (const float4*)(xs + r * 128);
#pragma unroll 4
  for (int k4 = 0; k4 < 32; ++k4) {
    float4 xv = xr4[k4];
#define STEPB(kk, comp)                                                      \
    {                                                                        \
      const float4* w = (const float4*)(WT + (k4 * 4 + kk) * 1280 + c0);     \
      float4 wA = w[0], wB = w[1];                                           \
      a[0] = fmaf(wA.x, comp, a[0]); a[1] = fmaf(wA.y, comp, a[1]);          \
      a[2] = fmaf(wA.z, comp, a[2]); a[3] = fmaf(wA.w, comp, a[3]);          \
      a[4] = fmaf(wB.x, comp, a[4]); a[5] = fmaf(wB.y, comp, a[5]);          \
      a[6] = fmaf(wB.z, comp, a[6]); a[7] = fmaf(wB.w, comp, a[7]);          \
    }
    STEPB(0, xv.x) STEPB(1, xv.y) STEPB(2, xv.z) STEPB(3, xv.w)
#undef STEPB
  }
  const int row = rt * 8 + r;          // = b*128 + t
  const int b = row >> 7, t = row & 127;
  if (ct < 4) {
    float* dst = xg2 + (size_t)(t * 32 + b) * 1024 + ct * 256 + cg * 8;
#pragma unroll
    for (int i = 0; i < 8; ++i) dst[i] = a[i];
  } else {
    float* dst = bx2 + (size_t)(t * 32 + b) * 256 + cg * 8;
#pragma unroll
    for (int i = 0; i < 8; ++i) dst[i] = a[i];
  }
}

// ---------------- recurrence, batch-partitioned: 512 blocks ----------------
// blocks [0,256): LSTM, b = bix>>3, cb = bix&7, owns dims [32cb, 32cb+32)
// blocks [256,512): cfc, same mapping. Fan-in 8 (own batch peers only).
__global__ __launch_bounds__(256) void recur_bp_kernel(
    const float* __restrict__ ts_all, const float* __restrict__ tau,
    const float* __restrict__ sigma, const float* __restrict__ W_hh,
    const float* __restrict__ W_A, const float* __restrict__ M2,
    const float* __restrict__ xg2, const float* __restrict__ bx2,
    float* __restrict__ hseq, float* __restrict__ hcseq) {
  const int tid = threadIdx.x;
  const unsigned long long* hsq  = (const unsigned long long*)hseq;
  const unsigned long long* hcsq = (const unsigned long long*)hcseq;

  __shared__ float h_s[256];     // staged state (h or hc)
  __shared__ float gv_s[128];    // lstm gate dots
  __shared__ float q_s[768];     // cfc q vector
  __shared__ float red_c[32 * 9];// cfc partials [r][kq8], pad 9

  if (blockIdx.x < 256) {
    // ===================== LSTM (batch b, dims 32cb..) =====================
    const int b = blockIdx.x >> 3, cb = blockIdx.x & 7;
    const int col = tid >> 1, kh = tid & 1;       // col in [0,128): gate*32+j
    const int grow = (col >> 5) * 256 + cb * 32 + (col & 31);
    float4 wq[32];
    {
      const float4* src = (const float4*)(W_hh + grow * 256 + kh * 128);
#pragma unroll
      for (int k4 = 0; k4 < 32; ++k4) wq[k4] = src[k4];
    }
    float c_reg = 0.f;

    for (int t = 0; t < T_; ++t) {
      // prefetch this step's xg (independent of the poll -> overlaps latency)
      float xg0 = 0.f, xg1 = 0.f, xg2v = 0.f, xg3 = 0.f;
      if (tid < 32) {
        const float* xp = xg2 + (size_t)(t * 32 + b) * 1024 + cb * 32 + tid;
        xg0 = xp[0]; xg1 = xp[256]; xg2v = xp[512]; xg3 = xp[768];
      }
      if (t == 0) {
        if (tid < 128) ((float2*)h_s)[tid] = make_float2(0.f, 0.f);
      } else if (tid < 128) {
        const unsigned long long* p = hsq + (size_t)((t - 1) * 32 + b) * 128 + tid;
        unsigned long long v = aload_u64(p);
        int spins = 0;
        while (bad_u64(v)) {
          if (++spins > 16) __builtin_amdgcn_s_sleep(1);
          v = aload_u64(p);
        }
        union { unsigned long long u; float2 f; } H; H.u = v;
        ((float2*)h_s)[tid] = H.f;
      }
      __syncthreads();

      // matvec: broadcast h reads (2 addrs/instr), weights in VGPRs
      const float4* h4 = (const float4*)(h_s + kh * 128);
      float s = 0.f;
#pragma unroll
      for (int k4 = 0; k4 < 32; ++k4) {
        const float4 w = wq[k4], hv = h4[k4];
        s = fmaf(w.x, hv.x, s); s = fmaf(w.y, hv.y, s);
        s = fmaf(w.z, hv.z, s); s = fmaf(w.w, hv.w, s);
      }
      s += __shfl_xor(s, 1);            // combine the two k-halves
      if (kh == 0) gv_s[col] = s;
      __syncthreads();

      if (tid < 32) {
        const float i_ = sigm_f(gv_s[tid]      + xg0);
        const float f_ = sigm_f(gv_s[32 + tid] + xg1);
        const float g_ = tanh_f(gv_s[64 + tid] + xg2v);
        const float o_ = sigm_f(gv_s[96 + tid] + xg3);
        c_reg = fmaf(f_, c_reg, i_ * g_);
        const float ht = o_ * tanh_f(c_reg);
        astore_f(hseq + (size_t)(t * 32 + b) * 256 + cb * 32 + tid, ht);
      }
      // 2 barriers/step: h_s rewrite (next stage) is after this iter's B2;
      // gv_s rewrite is after next B1, which finalize threads join when done.
    }
  } else {
    // ===================== cfc (batch b, rows 32cb..) =====================
    const int bix = blockIdx.x - 256;
    const int b = bix >> 3, cb = bix & 7;
    const int r = tid & 31, kq8 = tid >> 5;       // row r, k-chunk kq8 (96 wide)
    const int ci = cb * 32 + r;
    const float it_i = 1.0f / tau[ci];
    float4 wcf[24];
#pragma unroll
    for (int i4 = 0; i4 < 24; ++i4) {
      float v[4];
#pragma unroll
      for (int e = 0; e < 4; ++e) {
        const int kp = kq8 * 96 + i4 * 4 + e;
        if (kp < 256)      v[e] = W_A[ci * 256 + kp] / tau[kp];
        else if (kp < 512) v[e] = W_A[ci * 256 + (kp - 256)] * it_i;
        else               v[e] = 0.5f * M2[ci * 256 + (kp - 512)];
      }
      wcf[i4] = make_float4(v[0], v[1], v[2], v[3]);
    }
    const float isig = 1.0f / sigma[tid];

    for (int t = 0; t < T_; ++t) {
      const float ts = ts_all[b * T_ + t];   // broadcast
      float bx_v = 0.f;
      if (tid < 32)
        bx_v = bx2[(size_t)(t * 32 + b) * 256 + cb * 32 + tid];

      if (t == 0) {
        if (tid < 128) ((float2*)h_s)[tid] = make_float2(0.f, 0.f);
      } else if (tid < 128) {
        const unsigned long long* p = hcsq + (size_t)((t - 1) * 32 + b) * 128 + tid;
        unsigned long long v = aload_u64(p);
        int spins = 0;
        while (bad_u64(v)) {
          if (++spins > 16) __builtin_amdgcn_s_sleep(1);
          v = aload_u64(p);
        }
        union { unsigned long long u; float2 f; } C; C.u = v;
        ((float2*)h_s)[tid] = C.f;
      }
      __syncthreads();

      // q build (+ capture own hc for the I-term BEFORE hc can be rewritten)
      float hc_own = 0.f;
      if (tid < 32) hc_own = h_s[cb * 32 + tid];
      {
        const float hv = h_s[tid];
        q_s[tid]       = ts * hv;
        q_s[256 + tid] = ts * tanh_f(hv * isig);
        q_s[512 + tid] = ts * (ts * hv);
      }
      __syncthreads();

      // matvec: q broadcast float4 reads, weights in VGPRs
      const float4* q4 = (const float4*)q_s;
      float s = 0.f;
#pragma unroll
      for (int i4 = 0; i4 < 24; ++i4) {
        const float4 w = wcf[i4], qv = q4[kq8 * 24 + i4];
        s = fmaf(w.x, qv.x, s); s = fmaf(w.y, qv.y, s);
        s = fmaf(w.z, qv.z, s); s = fmaf(w.w, qv.w, s);
      }
      red_c[r * 9 + kq8] = s;
      __syncthreads();

      if (tid < 32) {
        float dot = 0.f;
#pragma unroll
        for (int k = 0; k < 8; ++k) dot += red_c[tid * 9 + k];
        // one-way ht(t) hand-off from the paired LSTM block (usually ready)
        const float* hp = hseq + (size_t)(t * 32 + b) * 256 + cb * 32 + tid;
        union { float f; unsigned u; } H;
        H.f = aload_f(hp);
        int spins = 0;
        while (H.u == SENTB) {
          if (++spins > 16) __builtin_amdgcn_s_sleep(1);
          H.f = aload_f(hp);
        }
        const float hn = hc_own + dot + ts * bx_v * it_i + H.f;
        astore_f(hcseq + (size_t)(t * 32 + b) * 256 + cb * 32 + tid, hn);
      }
      // no trailing barrier needed: h_s rewrite (next stage) races with nothing
      // (hc_own captured early); q_s/red_c rewrites are behind next B1/B2.
    }
  }
}

// ---------------- y = hc @ W_C^T + b_C (reads hcseq [t][b][256]) ----------------
__global__ __launch_bounds__(256) void out_kernel(
    const float* __restrict__ hc, const float* __restrict__ WCT,
    const float* __restrict__ bC, float* __restrict__ y) {
  __shared__ float hs[16 * 256];
  const int tid = threadIdx.x;
#pragma unroll
  for (int v = 0; v < 4; ++v) {
    const int flat = v * 256 + tid;
    const int r = flat >> 6, f4 = flat & 63;
    const int row = blockIdx.x * 16 + r;   // = b*128 + t
    const int b = row >> 7, t = row & 127;
    ((float4*)hs)[flat] = ((const float4*)(hc + (size_t)(t * 32 + b) * 256))[f4];
  }
  __syncthreads();
  const int r = tid >> 4, cgg = tid & 15;
  const int c0 = cgg * 8;
  const float4* b4 = (const float4*)(bC + c0);
  float4 bA = b4[0], bB = b4[1];
  float a0 = bA.x, a1 = bA.y, a2 = bA.z, a3 = bA.w;
  float a4 = bB.x, a5 = bB.y, a6 = bB.z, a7 = bB.w;
  const float4* hr4 = (const float4*)(hs + r * 256);
#pragma unroll 4
  for (int k4 = 0; k4 < 64; ++k4) {
    float4 hv = hr4[k4];
#define STEPD(kk, comp)                                                     \
    {                                                                       \
      const float4* w = (const float4*)(WCT + (k4 * 4 + kk) * 128 + c0);    \
      float4 wA = w[0], wB = w[1];                                          \
      a0 = fmaf(wA.x, comp, a0); a1 = fmaf(wA.y, comp, a1);                 \
      a2 = fmaf(wA.z, comp, a2); a3 = fmaf(wA.w, comp, a3);                 \
      a4 = fmaf(wB.x, comp, a4); a5 = fmaf(wB.y, comp, a5);                 \
      a6 = fmaf(wB.z, comp, a6); a7 = fmaf(wB.w, comp, a7);                 \
    }
    STEPD(0, hv.x) STEPD(1, hv.y) STEPD(2, hv.z) STEPD(3, hv.w)
#undef STEPD
  }
  const int row = blockIdx.x * 16 + r;
  float4* dst = (float4*)(y + (size_t)row * 128 + c0);
  dst[0] = make_float4(a0, a1, a2, a3);
  dst[1] = make_float4(a4, a5, a6, a7);
}

extern "C" void kernel_launch(void* const* d_in, const int* in_sizes, int n_in,
                              void* d_out, int out_size, void* d_ws, size_t ws_size,
                              hipStream_t stream) {
  const float* x     = (const float*)d_in[0];
  const float* tspan = (const float*)d_in[1];
  const float* tau   = (const float*)d_in[2];
  const float* sigma = (const float*)d_in[3];
  const float* W_A   = (const float*)d_in[4];
  const float* W_B   = (const float*)d_in[5];
  const float* b_B   = (const float*)d_in[6];
  const float* W_C   = (const float*)d_in[7];
  const float* b_C   = (const float*)d_in[8];
  const float* W_ih  = (const float*)d_in[9];
  const float* W_hh  = (const float*)d_in[10];
  const float* b_ih  = (const float*)d_in[11];
  const float* b_hh  = (const float*)d_in[12];
  float* ws = (float*)d_ws;
  float* y = (float*)d_out;

  // sentinel-fill hseq+hcseq (0xFF bytes == SENTB dwords), 8 MB
  (void)hipMemsetAsync(ws + OFF_HSEQ, 0xFF, (size_t)2 * 1048576 * sizeof(float), stream);
  pack_kernel<<<774, 256, 0, stream>>>(W_ih, W_B, b_ih, b_hh, b_B, W_C, ws);
  m2_kernel<<<256, 256, 0, stream>>>(W_A, tau, ws + OFF_M2);
  xgt_kernel<<<dim3(512, 5), 256, 0, stream>>>(x, ws + OFF_WCOMBT, ws + OFF_BIAS,
                                               ws + OFF_XG2, ws + OFF_BX2);
  recur_bp_kernel<<<512, 256, 0, stream>>>(
      tspan, tau, sigma, W_hh, W_A, ws + OFF_M2, ws + OFF_XG2, ws + OFF_BX2,
      ws + OFF_HSEQ, ws + OFF_HCSEQ);
  out_kernel<<<256, 256, 0, stream>>>(ws + OFF_HCSEQ, ws + OFF_WCT, b_C, y);
}

// Round 7
// 471.981 us; speedup vs baseline: 1.5070x; 1.0213x over previous
//
#include <hip/hip_runtime.h>
#include <math.h>

#define T_ 128

// ws offsets (floats)
#define OFF_M2      0         // [256][256]
#define OFF_WCOMBT  65536     // [128][1280]
#define OFF_BIAS    229376    // [1280]
#define OFF_WCT     230656    // [256][128]
#define OFF_XG2     263424    // [128 t][32 b][1024 c]   (gate-major: c = gate*256+d)
#define OFF_BX2     4457728   // [128 t][32 b][256 d]
#define OFF_HSEQ    5506304   // [128 t][32 b][256 d]  (ht from LSTM chain)
#define OFF_HCSEQ   6554880   // [128 t][32 b][256 d]  (hn_partial from cfc chain)

#define SENTB 0xFFFFFFFFu

__device__ __forceinline__ float sigm_f(float x) { return 1.0f / (1.0f + __expf(-x)); }
__device__ __forceinline__ float tanh_f(float x) { return 1.0f - 2.0f / (__expf(2.0f * x) + 1.0f); }

__device__ __forceinline__ unsigned long long aload_u64(const unsigned long long* p) {
  return __hip_atomic_load(p, __ATOMIC_RELAXED, __HIP_MEMORY_SCOPE_AGENT);
}
__device__ __forceinline__ void astore_f(float* p, float v) {
  __hip_atomic_store(p, v, __ATOMIC_RELAXED, __HIP_MEMORY_SCOPE_AGENT);
}
__device__ __forceinline__ bool bad_u64(unsigned long long v) {
  return (unsigned)v == SENTB || (unsigned)(v >> 32) == SENTB;
}

// ---------------- pack: WcombT, bias, W_C^T ----------------
__global__ __launch_bounds__(256) void pack_kernel(
    const float* __restrict__ W_ih, const float* __restrict__ W_B,
    const float* __restrict__ b_ih, const float* __restrict__ b_hh,
    const float* __restrict__ b_B,  const float* __restrict__ W_C,
    float* __restrict__ ws) {
  int idx = blockIdx.x * 256 + threadIdx.x;
  if (idx < 163840) {  // WcombT[k][c]
    int k = idx / 1280, c = idx - k * 1280;
    ws[OFF_WCOMBT + idx] = (c < 1024) ? W_ih[c * 128 + k] : W_B[(c - 1024) * 128 + k];
    return;
  }
  idx -= 163840;
  if (idx < 1280) {
    ws[OFF_BIAS + idx] = (idx < 1024) ? (b_ih[idx] + b_hh[idx]) : b_B[idx - 1024];
    return;
  }
  idx -= 1280;
  if (idx < 32768) {  // W_CT[k][o]
    int k = idx >> 7, o = idx & 127;
    ws[OFF_WCT + idx] = W_C[o * 256 + k];
  }
}

// ---------------- M2 = (W_A D)(W_A D), D = diag(1/tau) ----------------
__global__ __launch_bounds__(256) void m2_kernel(
    const float* __restrict__ W_A, const float* __restrict__ tau,
    float* __restrict__ M2) {
  __shared__ float adrow[256];
  const int i = blockIdx.x, k = threadIdx.x;
  const float itk = 1.0f / tau[k];
  adrow[k] = W_A[i * 256 + k] * itk;
  __syncthreads();
  float s = 0.f;
#pragma unroll 8
  for (int m = 0; m < 256; ++m)
    s = fmaf(adrow[m], W_A[m * 256 + k], s);
  M2[i * 256 + k] = s * itk;
}

// ---------------- xg/Bx precompute, batch-major layout ----------------
__global__ __launch_bounds__(256) void xgt_kernel(
    const float* __restrict__ x, const float* __restrict__ WT,
    const float* __restrict__ bias, float* __restrict__ xg2,
    float* __restrict__ bx2) {
  __shared__ float xs[8 * 128];
  const int tid = threadIdx.x;
  const int rt = blockIdx.x, ct = blockIdx.y;
  ((float4*)xs)[tid] = ((const float4*)(x + rt * 1024))[tid];
  __syncthreads();
  const int r = tid >> 5, cg = tid & 31;
  const int c0 = ct * 256 + cg * 8;
  const float4* b4 = (const float4*)(bias + c0);
  float4 bA = b4[0], bB = b4[1];
  float a[8] = {bA.x, bA.y, bA.z, bA.w, bB.x, bB.y, bB.z, bB.w};
  const float4* xr4 = (const float4*)(xs + r * 128);
#pragma unroll 4
  for (int k4 = 0; k4 < 32; ++k4) {
    float4 xv = xr4[k4];
#define STEPB(kk, comp)                                                      \
    {                                                                        \
      const float4* w = (const float4*)(WT + (k4 * 4 + kk) * 1280 + c0);     \
      float4 wA = w[0], wB = w[1];                                           \
      a[0] = fmaf(wA.x, comp, a[0]); a[1] = fmaf(wA.y, comp, a[1]);          \
      a[2] = fmaf(wA.z, comp, a[2]); a[3] = fmaf(wA.w, comp, a[3]);          \
      a[4] = fmaf(wB.x, comp, a[4]); a[5] = fmaf(wB.y, comp, a[5]);          \
      a[6] = fmaf(wB.z, comp, a[6]); a[7] = fmaf(wB.w, comp, a[7]);          \
    }
    STEPB(0, xv.x) STEPB(1, xv.y) STEPB(2, xv.z) STEPB(3, xv.w)
#undef STEPB
  }
  const int row = rt * 8 + r;          // = b*128 + t
  const int b = row >> 7, t = row & 127;
  if (ct < 4) {
    float* dst = xg2 + (size_t)(t * 32 + b) * 1024 + ct * 256 + cg * 8;
#pragma unroll
    for (int i = 0; i < 8; ++i) dst[i] = a[i];
  } else {
    float* dst = bx2 + (size_t)(t * 32 + b) * 256 + cg * 8;
#pragma unroll
    for (int i = 0; i < 8; ++i) dst[i] = a[i];
  }
}

// ---------------- recurrence, batch-partitioned: 512 blocks ----------------
// blocks [0,256): LSTM, b = bix>>3, cb = bix&7, owns dims [32cb, 32cb+32)
// blocks [256,512): cfc, same mapping. Fan-in 8 (own batch peers only).
// cfc stores hn_partial (no ht); consumers sum hcseq+hseq when staging.
__global__ __launch_bounds__(256) void recur_bp_kernel(
    const float* __restrict__ ts_all, const float* __restrict__ tau,
    const float* __restrict__ sigma, const float* __restrict__ W_hh,
    const float* __restrict__ W_A, const float* __restrict__ M2,
    const float* __restrict__ xg2, const float* __restrict__ bx2,
    float* __restrict__ hseq, float* __restrict__ hcseq) {
  const int tid = threadIdx.x;
  const unsigned long long* hsq  = (const unsigned long long*)hseq;
  const unsigned long long* hcsq = (const unsigned long long*)hcseq;

  __shared__ float h_s[256];     // staged state (h or true hc)
  __shared__ float gv_s[128];    // lstm gate dots
  __shared__ float q_s[768];     // cfc q vector
  __shared__ float red_c[32 * 9];// cfc partials [r][kq8], pad 9

  if (blockIdx.x < 256) {
    // ===================== LSTM (batch b, dims 32cb..) =====================
    const int b = blockIdx.x >> 3, cb = blockIdx.x & 7;
    const int col = tid >> 1, kh = tid & 1;       // col in [0,128): gate*32+j
    const int grow = (col >> 5) * 256 + cb * 32 + (col & 31);
    float4 wq[32];
    {
      const float4* src = (const float4*)(W_hh + grow * 256 + kh * 128);
#pragma unroll
      for (int k4 = 0; k4 < 32; ++k4) wq[k4] = src[k4];
    }
    float c_reg = 0.f;

    for (int t = 0; t < T_; ++t) {
      // prefetch this step's xg (independent of the poll -> overlaps latency)
      float xg0 = 0.f, xg1 = 0.f, xg2v = 0.f, xg3 = 0.f;
      if (tid < 32) {
        const float* xp = xg2 + (size_t)(t * 32 + b) * 1024 + cb * 32 + tid;
        xg0 = xp[0]; xg1 = xp[256]; xg2v = xp[512]; xg3 = xp[768];
      }
      if (t == 0) {
        if (tid < 128) ((float2*)h_s)[tid] = make_float2(0.f, 0.f);
      } else if (tid < 128) {
        const unsigned long long* p = hsq + (size_t)((t - 1) * 32 + b) * 128 + tid;
        unsigned long long v = aload_u64(p);
        int spins = 0;
        while (bad_u64(v)) {
          if (++spins > 16) __builtin_amdgcn_s_sleep(1);
          v = aload_u64(p);
        }
        union { unsigned long long u; float2 f; } H; H.u = v;
        ((float2*)h_s)[tid] = H.f;
      }
      __syncthreads();

      // matvec: broadcast h reads (2 addrs/instr), weights in VGPRs
      const float4* h4 = (const float4*)(h_s + kh * 128);
      float s = 0.f;
#pragma unroll
      for (int k4 = 0; k4 < 32; ++k4) {
        const float4 w = wq[k4], hv = h4[k4];
        s = fmaf(w.x, hv.x, s); s = fmaf(w.y, hv.y, s);
        s = fmaf(w.z, hv.z, s); s = fmaf(w.w, hv.w, s);
      }
      s += __shfl_xor(s, 1);            // combine the two k-halves
      if (kh == 0) gv_s[col] = s;
      __syncthreads();

      if (tid < 32) {
        const float i_ = sigm_f(gv_s[tid]      + xg0);
        const float f_ = sigm_f(gv_s[32 + tid] + xg1);
        const float g_ = tanh_f(gv_s[64 + tid] + xg2v);
        const float o_ = sigm_f(gv_s[96 + tid] + xg3);
        c_reg = fmaf(f_, c_reg, i_ * g_);
        const float ht = o_ * tanh_f(c_reg);
        astore_f(hseq + (size_t)(t * 32 + b) * 256 + cb * 32 + tid, ht);
      }
      // 2 barriers/step: h_s rewrite (next stage) is after this iter's B2;
      // gv_s rewrite is after next B1, which finalize threads join when done.
    }
  } else {
    // ===================== cfc (batch b, rows 32cb..) =====================
    const int bix = blockIdx.x - 256;
    const int b = bix >> 3, cb = bix & 7;
    const int r = tid & 31, kq8 = tid >> 5;       // row r, k-chunk kq8 (96 wide)
    const int ci = cb * 32 + r;
    const float it_i = 1.0f / tau[ci];
    float4 wcf[24];
#pragma unroll
    for (int i4 = 0; i4 < 24; ++i4) {
      float v[4];
#pragma unroll
      for (int e = 0; e < 4; ++e) {
        const int kp = kq8 * 96 + i4 * 4 + e;
        if (kp < 256)      v[e] = W_A[ci * 256 + kp] / tau[kp];
        else if (kp < 512) v[e] = W_A[ci * 256 + (kp - 256)] * it_i;
        else               v[e] = 0.5f * M2[ci * 256 + (kp - 512)];
      }
      wcf[i4] = make_float4(v[0], v[1], v[2], v[3]);
    }
    const float isig = 1.0f / sigma[tid];

    for (int t = 0; t < T_; ++t) {
      const float ts = ts_all[b * T_ + t];   // broadcast
      float bx_v = 0.f;
      if (tid < 32)
        bx_v = bx2[(size_t)(t * 32 + b) * 256 + cb * 32 + tid];

      if (t == 0) {
        if (tid < 128) ((float2*)h_s)[tid] = make_float2(0.f, 0.f);
      } else if (tid < 128) {
        // true hc(t-1) = hn_partial(t-1) + ht(t-1): poll BOTH in one flight
        const size_t base = (size_t)((t - 1) * 32 + b) * 128 + tid;
        const unsigned long long* pc = hcsq + base;
        const unsigned long long* ph = hsq + base;
        unsigned long long vc = aload_u64(pc);
        unsigned long long vh = aload_u64(ph);
        int spins = 0;
        while (bad_u64(vc) || bad_u64(vh)) {
          if (++spins > 16) __builtin_amdgcn_s_sleep(1);
          vc = aload_u64(pc);
          vh = aload_u64(ph);
        }
        union { unsigned long long u; float2 f; } C, H;
        C.u = vc; H.u = vh;
        ((float2*)h_s)[tid] = make_float2(C.f.x + H.f.x, C.f.y + H.f.y);
      }
      __syncthreads();

      // q build (+ capture own hc for the I-term BEFORE hc can be rewritten)
      float hc_own = 0.f;
      if (tid < 32) hc_own = h_s[cb * 32 + tid];
      {
        const float hv = h_s[tid];
        q_s[tid]       = ts * hv;
        q_s[256 + tid] = ts * tanh_f(hv * isig);
        q_s[512 + tid] = ts * (ts * hv);
      }
      __syncthreads();

      // matvec: q broadcast float4 reads, weights in VGPRs
      const float4* q4 = (const float4*)q_s;
      float s = 0.f;
#pragma unroll
      for (int i4 = 0; i4 < 24; ++i4) {
        const float4 w = wcf[i4], qv = q4[kq8 * 24 + i4];
        s = fmaf(w.x, qv.x, s); s = fmaf(w.y, qv.y, s);
        s = fmaf(w.z, qv.z, s); s = fmaf(w.w, qv.w, s);
      }
      red_c[r * 9 + kq8] = s;
      __syncthreads();

      if (tid < 32) {
        float dot = 0.f;
#pragma unroll
        for (int k = 0; k < 8; ++k) dot += red_c[tid * 9 + k];
        // NO ht wait: store hn_partial; consumers & out_kernel add ht themselves
        const float hn_p = hc_own + dot + ts * bx_v * it_i;
        astore_f(hcseq + (size_t)(t * 32 + b) * 256 + cb * 32 + tid, hn_p);
      }
      // no trailing barrier needed: h_s rewrite (next stage) races with nothing
      // (hc_own captured early); q_s/red_c rewrites are behind next B1/B2.
    }
  }
}

// ---------------- y = (hc_partial + ht) @ W_C^T + b_C ----------------
__global__ __launch_bounds__(256) void out_kernel(
    const float* __restrict__ hc, const float* __restrict__ ht,
    const float* __restrict__ WCT, const float* __restrict__ bC,
    float* __restrict__ y) {
  __shared__ float hs[16 * 256];
  const int tid = threadIdx.x;
#pragma unroll
  for (int v = 0; v < 4; ++v) {
    const int flat = v * 256 + tid;
    const int r = flat >> 6, f4 = flat & 63;
    const int row = blockIdx.x * 16 + r;   // = b*128 + t
    const int b = row >> 7, t = row & 127;
    const float4 a = ((const float4*)(hc + (size_t)(t * 32 + b) * 256))[f4];
    const float4 h = ((const float4*)(ht + (size_t)(t * 32 + b) * 256))[f4];
    ((float4*)hs)[flat] = make_float4(a.x + h.x, a.y + h.y, a.z + h.z, a.w + h.w);
  }
  __syncthreads();
  const int r = tid >> 4, cgg = tid & 15;
  const int c0 = cgg * 8;
  const float4* b4 = (const float4*)(bC + c0);
  float4 bA = b4[0], bB = b4[1];
  float a0 = bA.x, a1 = bA.y, a2 = bA.z, a3 = bA.w;
  float a4 = bB.x, a5 = bB.y, a6 = bB.z, a7 = bB.w;
  const float4* hr4 = (const float4*)(hs + r * 256);
#pragma unroll 4
  for (int k4 = 0; k4 < 64; ++k4) {
    float4 hv = hr4[k4];
#define STEPD(kk, comp)                                                     \
    {                                                                       \
      const float4* w = (const float4*)(WCT + (k4 * 4 + kk) * 128 + c0);    \
      float4 wA = w[0], wB = w[1];                                          \
      a0 = fmaf(wA.x, comp, a0); a1 = fmaf(wA.y, comp, a1);                 \
      a2 = fmaf(wA.z, comp, a2); a3 = fmaf(wA.w, comp, a3);                 \
      a4 = fmaf(wB.x, comp, a4); a5 = fmaf(wB.y, comp, a5);                 \
      a6 = fmaf(wB.z, comp, a6); a7 = fmaf(wB.w, comp, a7);                 \
    }
    STEPD(0, hv.x) STEPD(1, hv.y) STEPD(2, hv.z) STEPD(3, hv.w)
#undef STEPD
  }
  const int row = blockIdx.x * 16 + r;
  float4* dst = (float4*)(y + (size_t)row * 128 + c0);
  dst[0] = make_float4(a0, a1, a2, a3);
  dst[1] = make_float4(a4, a5, a6, a7);
}

extern "C" void kernel_launch(void* const* d_in, const int* in_sizes, int n_in,
                              void* d_out, int out_size, void* d_ws, size_t ws_size,
                              hipStream_t stream) {
  const float* x     = (const float*)d_in[0];
  const float* tspan = (const float*)d_in[1];
  const float* tau   = (const float*)d_in[2];
  const float* sigma = (const float*)d_in[3];
  const float* W_A   = (const float*)d_in[4];
  const float* W_B   = (const float*)d_in[5];
  const float* b_B   = (const float*)d_in[6];
  const float* W_C   = (const float*)d_in[7];
  const float* b_C   = (const float*)d_in[8];
  const float* W_ih  = (const float*)d_in[9];
  const float* W_hh  = (const float*)d_in[10];
  const float* b_ih  = (const float*)d_in[11];
  const float* b_hh  = (const float*)d_in[12];
  float* ws = (float*)d_ws;
  float* y = (float*)d_out;

  // sentinel-fill hseq+hcseq (0xFF bytes == SENTB dwords), 8 MB
  (void)hipMemsetAsync(ws + OFF_HSEQ, 0xFF, (size_t)2 * 1048576 * sizeof(float), stream);
  pack_kernel<<<774, 256, 0, stream>>>(W_ih, W_B, b_ih, b_hh, b_B, W_C, ws);
  m2_kernel<<<256, 256, 0, stream>>>(W_A, tau, ws + OFF_M2);
  xgt_kernel<<<dim3(512, 5), 256, 0, stream>>>(x, ws + OFF_WCOMBT, ws + OFF_BIAS,
                                               ws + OFF_XG2, ws + OFF_BX2);
  recur_bp_kernel<<<512, 256, 0, stream>>>(
      tspan, tau, sigma, W_hh, W_A, ws + OFF_M2, ws + OFF_XG2, ws + OFF_BX2,
      ws + OFF_HSEQ, ws + OFF_HCSEQ);
  out_kernel<<<256, 256, 0, stream>>>(ws + OFF_HCSEQ, ws + OFF_HSEQ,
                                      ws + OFF_WCT, b_C, y);
}